// Round 3
// baseline (470.464 us; speedup 1.0000x reference)
//
#include <hip/hip_runtime.h>

#define NUM_PROCS 16
#define PROC_DIM 8
#define SPATIAL_DIM 3
#define ROW_DIM (PROC_DIM + SPATIAL_DIM)   // 11
#define BLOCK 256
#define WAVES_PB (BLOCK / 64)              // 4 waves per block
#define TROWS 64                           // rows per wave-tile: 1 row per lane
#define TILE_F (TROWS * ROW_DIM)           // 704 floats = 2816 B (64B-aligned windows)
#define SPROC_STRIDE 12                    // padded proc rows: 16B-aligned ds_read_b128

typedef float v4f __attribute__((ext_vector_type(4)));

// Concurrency-decoupled gather pipeline:
//  - LDS holds only ONE 2816B tile per wave (slot is reusable as soon as the
//    ds_read for the store completes -- lgkmcnt, NOT store retirement), so LDS
//    no longer caps gather MLP. 12KB/block -> occupancy capped by threads:
//    8 blocks/CU = 32 waves/CU (needs VGPR<=64, hence launch_bounds(256,8)).
//  - depth-3 register-rotated gather pipeline: gathers for tiles t+1,t+2,t+3
//    sustained in flight while tile t stages+stores -> ~96 outstanding
//    scattered gathers/CU vs ~56 in rounds 0/2. This arbitrates
//    latency-bound (expect ~1.5-1.7x) vs MSHR-capped (expect flat).
//  - stores remain full-line wave-coalesced dwordx4 NT from LDS
//    (round-1 lesson: scattered NT stores -> 3.5x write amplification).
__global__ __launch_bounds__(BLOCK, 8) void gather_concat_kernel(
    const float* __restrict__ proc_pos,     // [16, 8]
    const float* __restrict__ locs_sp,      // [500000, 3]
    const int*   __restrict__ process_ids,  // [NAUG]
    const int*   __restrict__ location_ids, // [NAUG]
    float* __restrict__ out,                // [NAUG, 11]
    int naug)
{
    __shared__ float sproc[NUM_PROCS * SPROC_STRIDE];   // 768 B
    __shared__ float stage[WAVES_PB][TILE_F];           // 11264 B

    const int t    = threadIdx.x;
    const int wv   = t >> 6;
    const int lane = t & 63;

    if (t < NUM_PROCS * PROC_DIM)
        sproc[(t >> 3) * SPROC_STRIDE + (t & 7)] = proc_pos[t];
    __syncthreads();    // only barrier; waves independent afterwards

    const int WT = naug / TROWS;                 // full wave-tiles (125000 at 8M)
    const int NW = gridDim.x * WAVES_PB;         // tile stride across all waves
    const int gw = blockIdx.x * WAVES_PB + wv;   // global wave id

    float* const sl     = stage[wv];
    const v4f* const s4 = (const v4f*)sl;

    // guards are wave-uniform (wt uniform per wave) -> no divergence;
    // OOB defaults to index 0 -> gather hits locs_sp[0] (safe, L1-resident)
    auto ld_lid = [&](int w) -> int {
        return (w < WT) ? __builtin_nontemporal_load(location_ids + (size_t)w * TROWS + lane) : 0;
    };
    auto ld_pid = [&](int w) -> int {
        return (w < WT) ? __builtin_nontemporal_load(process_ids + (size_t)w * TROWS + lane) : 0;
    };

    // ---- prologue: fill the depth-3 pipeline (one-time ~2 chained latencies) ----
    int li0  = ld_lid(gw);
    int li1  = ld_lid(gw + NW);
    int li2  = ld_lid(gw + 2 * NW);
    int liA  = ld_lid(gw + 3 * NW);   // consumed by first body's gather issue
    int liB  = ld_lid(gw + 4 * NW);   // in flight
    int pidA = ld_pid(gw);
    int pidB = ld_pid(gw + NW);

    const float* g0 = locs_sp + (size_t)li0 * SPATIAL_DIM;
    const float* g1 = locs_sp + (size_t)li1 * SPATIAL_DIM;
    const float* g2 = locs_sp + (size_t)li2 * SPATIAL_DIM;
    float c0  = g0[0], c1  = g0[1], c2  = g0[2];   // tile t
    float n10 = g1[0], n11 = g1[1], n12 = g1[2];   // tile t+1 (in flight)
    float n20 = g2[0], n21 = g2[1], n22 = g2[2];   // tile t+2 (in flight)

    for (int wt = gw; wt < WT; wt += NW) {
        // index prefetch: lid 5 tiles ahead, pid 2 tiles ahead (load->use gap = 2 bodies)
        int liC   = ld_lid(wt + 5 * NW);
        int pidC_ = ld_pid(wt + 2 * NW);

        // issue gather for tile t+3: joins t+1, t+2 in flight (3 sustained per lane)
        const float* g3 = locs_sp + (size_t)liA * SPATIAL_DIM;
        float n30 = g3[0], n31 = g3[1], n32 = g3[2];

        // stage tile t. The wait for (c0,c1,c2) is a counted vmcnt (their load is
        // the oldest outstanding) -- newer gathers/stores stay in flight, no drain.
        const v4f* P = (const v4f*)(sproc + pidA * SPROC_STRIDE);
        v4f pa = P[0], pb = P[1];
        float* d = sl + lane * ROW_DIM;     // stride 11 dwords: 2-way banks, free
        d[0] = pa.x; d[1] = pa.y; d[2]  = pa.z; d[3] = pa.w;
        d[4] = pb.x; d[5] = pb.y; d[6]  = pb.z; d[7] = pb.w;
        d[8] = c0;   d[9] = c1;   d[10] = c2;

        // full-line coalesced NT store: 176 v4f, windows 2816 B = 44 whole lines.
        // unroll 1 keeps live VGPRs low (launch_bounds(256,8) needs <=64).
        v4f* out4 = (v4f*)(out + (size_t)wt * TILE_F);
        #pragma unroll 1
        for (int k = 0; k < 2; ++k) {
            const int i = lane + k * 64;
            __builtin_nontemporal_store(s4[i], out4 + i);
        }
        if (lane < 48) {
            const int i = 128 + lane;
            __builtin_nontemporal_store(s4[i], out4 + i);
        }

        // rotate pipeline registers (all statically named -> pure renaming)
        c0  = n10; c1  = n11; c2  = n12;
        n10 = n20; n11 = n21; n12 = n22;
        n20 = n30; n21 = n31; n22 = n32;
        liA = liB; liB = liC;
        pidA = pidB; pidB = pidC_;
    }

    // scalar cleanup for naug % TROWS (empty at NAUG = 8M)
    const int tail0 = WT * TROWS;
    if (gw == 0) {
        for (int r = tail0 + lane; r < naug; r += 64) {
            const int pid = process_ids[r];
            const int lid = location_ids[r];
            const float* ps = sproc + pid * SPROC_STRIDE;
            const float* ls = locs_sp + (size_t)lid * SPATIAL_DIM;
            float* orow = out + (size_t)r * ROW_DIM;
            #pragma unroll
            for (int j = 0; j < PROC_DIM; ++j) orow[j] = ps[j];
            orow[8] = ls[0]; orow[9] = ls[1]; orow[10] = ls[2];
        }
    }
}

extern "C" void kernel_launch(void* const* d_in, const int* in_sizes, int n_in,
                              void* d_out, int out_size, void* d_ws, size_t ws_size,
                              hipStream_t stream) {
    const float* proc_pos     = (const float*)d_in[0];
    const float* locs_sp      = (const float*)d_in[1];
    const int*   process_ids  = (const int*)d_in[2];
    const int*   location_ids = (const int*)d_in[3];
    float* out = (float*)d_out;

    const int naug = in_sizes[2];   // 8,000,000
    const int WT   = naug / TROWS;  // 125000 wave-tiles

    // 8 blocks/CU x 256 CU = 2048 blocks (32 waves/CU); each wave ~15 tiles.
    int grid = 2048;
    const int maxg = (WT + WAVES_PB - 1) / WAVES_PB;
    if (maxg >= 1 && grid > maxg) grid = maxg;
    if (grid < 1) grid = 1;

    gather_concat_kernel<<<grid, BLOCK, 0, stream>>>(
        proc_pos, locs_sp, process_ids, location_ids, out, naug);
}

// Round 4
// 456.974 us; speedup vs baseline: 1.0295x; 1.0295x over previous
//
#include <hip/hip_runtime.h>

#define NUM_PROCS 16
#define PROC_DIM 8
#define SPATIAL_DIM 3
#define ROW_DIM (PROC_DIM + SPATIAL_DIM)   // 11
#define BLOCK 256
#define RPT 2                               // rows per thread (consecutive pair)
#define ROWS_PER_BLOCK (BLOCK * RPT)        // 512; 8,000,000 / 512 = 15625 exactly
#define SPROC_STRIDE 12                     // padded proc rows: 16B-aligned ds_read_b128,
                                            // pids spread 8 bank-slots (~2-way, free)
#define N_LOCS 500000                       // problem constant (like NUM_PROCS)

typedef float v4f __attribute__((ext_vector_type(4)));
typedef int   v2i __attribute__((ext_vector_type(2)));

// One-time table pad: [N][3] f32 -> [N][4] f32 in workspace. Makes every gather a
// 16B-aligned dwordx4 touching EXACTLY one 64B line (12B rows straddle lines for
// 2/16 of lids -> 1.125 lines/gather). Under the measured fill-count cap
// (~14.6 cy/line/CU, flat vs concurrency across R0/R2/R3) this is the only
// permutation-free lever left: -11% line fills.
__global__ __launch_bounds__(256) void pad_table_kernel(
    const float* __restrict__ src, float* __restrict__ dst, int n)
{
    const int i = blockIdx.x * blockDim.x + threadIdx.x;
    if (i < n) {
        const float* s = src + (size_t)i * 3;
        v4f r; r.x = s[0]; r.y = s[1]; r.z = s[2]; r.w = 0.0f;
        ((v4f*)dst)[i] = r;   // contiguous 16B/lane, coalesced
    }
}

// Round-0 champion structure (one-shot block, full-tile LDS stage, coalesced NT
// stores) -- the best measured operating point (kernel slice ~222us). Pipelined
// variants (R2 depth-2, R3 depth-3) were flat-to-worse: gather service is
// fill-count/MSHR-capped, not ILP-limited. PADDED selects the ws gather table.
template<bool PADDED>
__global__ __launch_bounds__(BLOCK) void gather_concat_kernel(
    const float* __restrict__ proc_pos,     // [16, 8]
    const float* __restrict__ locs_sp,      // [N_LOCS, 3] original
    const float* __restrict__ tab4,         // [N_LOCS, 4] padded (ws) if PADDED
    const int*   __restrict__ process_ids,  // [NAUG]
    const int*   __restrict__ location_ids, // [NAUG]
    float* __restrict__ out,                // [NAUG, 11]
    int naug)
{
    __shared__ float sproc[NUM_PROCS * SPROC_STRIDE];   // 768 B
    __shared__ float s[ROWS_PER_BLOCK * ROW_DIM];       // 22528 B -> 6 blocks/CU

    const int t = threadIdx.x;
    const int block_row0 = blockIdx.x * ROWS_PER_BLOCK;
    const bool full = (block_row0 + ROWS_PER_BLOCK <= naug);

    // Stage proc table (128 dwords) with padded stride.
    if (t < NUM_PROCS * PROC_DIM)
        sproc[(t >> 3) * SPROC_STRIDE + (t & 7)] = proc_pos[t];

    // Vectorized NT index loads: thread t owns rows 2t, 2t+1 of the window.
    const int r0 = block_row0 + 2 * t;
    v2i pid2, lid2;
    if (full) {
        pid2 = __builtin_nontemporal_load((const v2i*)(process_ids + block_row0) + t);
        lid2 = __builtin_nontemporal_load((const v2i*)(location_ids + block_row0) + t);
    } else {
        pid2.x = (r0     < naug) ? process_ids[r0]     : 0;
        pid2.y = (r0 + 1 < naug) ? process_ids[r0 + 1] : 0;
        lid2.x = (r0     < naug) ? location_ids[r0]     : 0;
        lid2.y = (r0 + 1 < naug) ? location_ids[r0 + 1] : 0;
    }

    // Scattered gathers issued BEFORE the staging barrier (latency overlaps it).
    float a0, a1, a2, b0, b1, b2;
    if (PADDED) {
        v4f g0 = ((const v4f*)tab4)[lid2.x];   // 1 aligned line, always
        v4f g1 = ((const v4f*)tab4)[lid2.y];
        a0 = g0.x; a1 = g0.y; a2 = g0.z;
        b0 = g1.x; b1 = g1.y; b2 = g1.z;
    } else {
        const float* lp0 = locs_sp + (size_t)lid2.x * SPATIAL_DIM;
        const float* lp1 = locs_sp + (size_t)lid2.y * SPATIAL_DIM;
        a0 = lp0[0]; a1 = lp0[1]; a2 = lp0[2];
        b0 = lp1[0]; b1 = lp1[1]; b2 = lp1[2];
    }

    __syncthreads();   // sproc ready

    // Proc fragments from LDS: 2x ds_read_b128 per row, stride-12 bank spread.
    const v4f* pp0 = (const v4f*)(sproc + pid2.x * SPROC_STRIDE);
    const v4f* pp1 = (const v4f*)(sproc + pid2.y * SPROC_STRIDE);
    v4f p00 = pp0[0], p01 = pp0[1];
    v4f p10 = pp1[0], p11 = pp1[1];

    // Row writes at stride 22 words across lanes: ~4-way aliasing, acceptable.
    float* d0 = s + (size_t)(2 * t) * ROW_DIM;
    d0[0] = p00.x; d0[1] = p00.y; d0[2]  = p00.z; d0[3] = p00.w;
    d0[4] = p01.x; d0[5] = p01.y; d0[6]  = p01.z; d0[7] = p01.w;
    d0[8] = a0;    d0[9] = a1;    d0[10] = a2;
    float* d1 = d0 + ROW_DIM;
    d1[0] = p10.x; d1[1] = p10.y; d1[2]  = p10.z; d1[3] = p10.w;
    d1[4] = p11.x; d1[5] = p11.y; d1[6]  = p11.z; d1[7] = p11.w;
    d1[8] = b0;    d1[9] = b1;    d1[10] = b2;

    __syncthreads();

    // Full-line wave-coalesced NT stores: 1408 v4f, 1024 B/wave-instruction.
    // (R1 lesson: scattered NT stores -> 3.5x write amplification + RMW fetch.)
    const v4f* s4 = (const v4f*)s;
    if (full) {
        v4f* out4 = (v4f*)(out + (size_t)block_row0 * ROW_DIM);
        #pragma unroll
        for (int k = 0; k < (ROWS_PER_BLOCK * ROW_DIM) / 4 / BLOCK; ++k) {   // 5
            const int i = t + k * BLOCK;
            __builtin_nontemporal_store(s4[i], out4 + i);
        }
        const int i = t + ((ROWS_PER_BLOCK * ROW_DIM) / 4 / BLOCK) * BLOCK;
        if (i < (ROWS_PER_BLOCK * ROW_DIM) / 4) {                             // 128 lanes
            __builtin_nontemporal_store(s4[i], out4 + i);
        }
    } else {
        const int total_f = (naug - block_row0) * ROW_DIM;
        float* outf = out + (size_t)block_row0 * ROW_DIM;
        for (int i = t; i < total_f; i += BLOCK) {
            outf[i] = s[i];
        }
    }
}

extern "C" void kernel_launch(void* const* d_in, const int* in_sizes, int n_in,
                              void* d_out, int out_size, void* d_ws, size_t ws_size,
                              hipStream_t stream) {
    const float* proc_pos     = (const float*)d_in[0];
    const float* locs_sp      = (const float*)d_in[1];
    const int*   process_ids  = (const int*)d_in[2];
    const int*   location_ids = (const int*)d_in[3];
    float* out = (float*)d_out;

    const int naug = in_sizes[2];   // 8,000,000
    const int grid = (naug + ROWS_PER_BLOCK - 1) / ROWS_PER_BLOCK;

    const size_t pad_bytes = (size_t)N_LOCS * 4 * sizeof(float);   // 8 MB
    if (d_ws != nullptr && ws_size >= pad_bytes) {
        float* tab4 = (float*)d_ws;
        pad_table_kernel<<<(N_LOCS + 255) / 256, 256, 0, stream>>>(
            locs_sp, tab4, N_LOCS);
        gather_concat_kernel<true><<<grid, BLOCK, 0, stream>>>(
            proc_pos, locs_sp, tab4, process_ids, location_ids, out, naug);
    } else {
        gather_concat_kernel<false><<<grid, BLOCK, 0, stream>>>(
            proc_pos, locs_sp, locs_sp, process_ids, location_ids, out, naug);
    }
}

// Round 5
// 449.309 us; speedup vs baseline: 1.0471x; 1.0171x over previous
//
#include <hip/hip_runtime.h>
#include <hip/hip_bf16.h>

#define NUM_PROCS 16
#define PROC_DIM 8
#define SPATIAL_DIM 3
#define ROW_DIM (PROC_DIM + SPATIAL_DIM)   // 11
#define BLOCK 256
#define RPT 2                               // rows per thread (consecutive pair)
#define ROWS_PER_BLOCK (BLOCK * RPT)        // 512; 8,000,000 / 512 = 15625 exactly

// clang native vector types: accepted by __builtin_nontemporal_{load,store}
typedef float v4f __attribute__((ext_vector_type(4)));
typedef int   v2i __attribute__((ext_vector_type(2)));

// SESSION-FINAL kernel — measured champion (448.7 us total; kernel slice ~222 us).
// Structure: one-shot block, full-tile LDS stage, full-line wave-coalesced NT stores.
// Negative results that define the roofline (do not re-litigate without new HW info):
//  - R1: direct scattered 16B NT stores -> 3.5x write amplification + RMW fetches
//    (1.24 GB WRITE vs 352 MB ideal). LDS store-staging is mandatory.
//  - R2/R3: sustained gather pipelines (depth 2/3, up to 32 waves/CU, ~96 gathers
//    in flight/CU) -> flat-to-worse. Gather service is capped ~14.6 cy/line/CU
//    (TCP MSHR x blended latency), not ILP-limited.
//  - R4: 16B-padded gather table (-11% line fills) -> null; footprint 6->8 MB
//    lowers L2 hit rate, canceling the fill reduction.
// Kernel floor ~= 36.5K line fills/CU x ~14.6 cy ≈ 200 us; we sit ~10% above it.
__global__ __launch_bounds__(BLOCK) void gather_concat_kernel(
    const float* __restrict__ proc_pos,     // [16, 8]
    const float* __restrict__ locs_sp,      // [500000, 3]
    const int*   __restrict__ process_ids,  // [NAUG]
    const int*   __restrict__ location_ids, // [NAUG]
    float* __restrict__ out,                // [NAUG, 11]
    int naug)
{
    __shared__ float sproc[NUM_PROCS * PROC_DIM];   // 512 B, staged once per block
    __shared__ float s[ROWS_PER_BLOCK * ROW_DIM];   // 22528 B -> 7 blocks/CU

    const int t = threadIdx.x;
    const int block_row0 = blockIdx.x * ROWS_PER_BLOCK;
    const bool full = (block_row0 + ROWS_PER_BLOCK <= naug);

    // Stage the whole proc table into LDS (128 dwords, threads 0..127).
    if (t < NUM_PROCS * PROC_DIM) sproc[t] = proc_pos[t];

    // Vectorized index loads: thread t owns rows 2t, 2t+1 of the block window.
    // int2 = 8 B/lane, 512 B/wave contiguous, NT (streamed once).
    const int r0 = block_row0 + 2 * t;
    v2i pid2, lid2;
    if (full) {
        pid2 = __builtin_nontemporal_load((const v2i*)(process_ids + block_row0) + t);
        lid2 = __builtin_nontemporal_load((const v2i*)(location_ids + block_row0) + t);
    } else {
        pid2.x = (r0     < naug) ? process_ids[r0]     : 0;
        pid2.y = (r0 + 1 < naug) ? process_ids[r0 + 1] : 0;
        lid2.x = (r0     < naug) ? location_ids[r0]     : 0;
        lid2.y = (r0 + 1 < naug) ? location_ids[r0 + 1] : 0;
    }

    // Issue the scattered locs gathers (the only compulsory global gathers)
    // BEFORE the staging barrier so their latency overlaps it.
    const float* lp0 = locs_sp + (size_t)lid2.x * SPATIAL_DIM;
    const float* lp1 = locs_sp + (size_t)lid2.y * SPATIAL_DIM;
    float a0 = lp0[0], a1 = lp0[1], a2 = lp0[2];
    float b0 = lp1[0], b1 = lp1[1], b2 = lp1[2];

    __syncthreads();   // sproc ready

    // Proc fragments from LDS: pid*32 B base, ds_read_b128 x2.
    // 16 distinct pids x 4 banks = avg 2-way aliasing -> free (m136).
    const v4f* pp0 = (const v4f*)(sproc + pid2.x * PROC_DIM);
    const v4f* pp1 = (const v4f*)(sproc + pid2.y * PROC_DIM);
    v4f p00 = pp0[0], p01 = pp0[1];
    v4f p10 = pp1[0], p11 = pp1[1];

    // Row writes at stride 22 words across lanes: 4-way bank aliasing (1.58x),
    // acceptable for 22 dword-writes/thread.
    float* d0 = s + (size_t)(2 * t) * ROW_DIM;
    d0[0] = p00.x; d0[1] = p00.y; d0[2] = p00.z; d0[3] = p00.w;
    d0[4] = p01.x; d0[5] = p01.y; d0[6] = p01.z; d0[7] = p01.w;
    d0[8] = a0;    d0[9] = a1;    d0[10] = a2;
    float* d1 = d0 + ROW_DIM;
    d1[0] = p10.x; d1[1] = p10.y; d1[2] = p10.z; d1[3] = p10.w;
    d1[4] = p11.x; d1[5] = p11.y; d1[6] = p11.z; d1[7] = p11.w;
    d1[8] = b0;    d1[9] = b1;    d1[10] = b2;

    __syncthreads();

    // Stream 512*11 = 5632 floats = 1408 v4f to global, fully coalesced.
    // Base byte offset = blockIdx * 22528 (16B-aligned). Non-temporal:
    // output is write-once; keep L2/L3 for the locs_sp gather table.
    const v4f* s4 = (const v4f*)s;
    if (full) {
        v4f* out4 = (v4f*)(out + (size_t)block_row0 * ROW_DIM);
        #pragma unroll
        for (int k = 0; k < (ROWS_PER_BLOCK * ROW_DIM) / 4 / BLOCK; ++k) {   // 5
            const int i = t + k * BLOCK;
            __builtin_nontemporal_store(s4[i], out4 + i);
        }
        const int i = t + ((ROWS_PER_BLOCK * ROW_DIM) / 4 / BLOCK) * BLOCK;
        if (i < (ROWS_PER_BLOCK * ROW_DIM) / 4) {                             // 128 lanes
            __builtin_nontemporal_store(s4[i], out4 + i);
        }
    } else {
        // generic tail block (not hit for NAUG=8M)
        const int total_f = (naug - block_row0) * ROW_DIM;
        float* outf = out + (size_t)block_row0 * ROW_DIM;
        for (int i = t; i < total_f; i += BLOCK) {
            outf[i] = s[i];
        }
    }
}

extern "C" void kernel_launch(void* const* d_in, const int* in_sizes, int n_in,
                              void* d_out, int out_size, void* d_ws, size_t ws_size,
                              hipStream_t stream) {
    const float* proc_pos     = (const float*)d_in[0];
    const float* locs_sp      = (const float*)d_in[1];
    const int*   process_ids  = (const int*)d_in[2];
    const int*   location_ids = (const int*)d_in[3];
    float* out = (float*)d_out;

    const int naug = in_sizes[2];   // 8,000,000
    const int grid = (naug + ROWS_PER_BLOCK - 1) / ROWS_PER_BLOCK;

    gather_concat_kernel<<<grid, BLOCK, 0, stream>>>(
        proc_pos, locs_sp, process_ids, location_ids, out, naug);
}